// Round 4
// baseline (975.828 us; speedup 1.0000x reference)
//
#include <hip/hip_runtime.h>

// GraphSAGE 2-layer, N=100000, E=1600000, 128 -> 64 -> 32.
// Round 4: transforms rewritten — LDS-staged node tiles + batched-node inner
// loop with small register footprint (round-3 version hit VGPR=256 ->
// occupancy 10.8% -> latency-bound broadcast loads, 195 us for a 5 us GEMM).

namespace {
constexpr int N = 100000;
constexpr int E = 1600000;
constexpr long long NF64 = (long long)N * 64;   // 6,400,000
constexpr long long NF32 = (long long)N * 32;
constexpr int NBLK = (N + 255) / 256;           // 391 scan blocks
constexpr int T1_TILES = N / 32;                // 3125 (N % 32 == 0)
constexpr int T2_TILES = (N + 63) / 64;         // 1563
}

// ---------------- CSR build ----------------

// int64 vs int32 edge dtype: high 32-bit words of int64 entries are all zero
// (node ids < 2^31); for int32 data they are random ids. Sample 16384 words,
// single block, one plain store (round-2 version was a 286 us atomic storm).
__global__ __launch_bounds__(256) void detect_dtype(const int* __restrict__ raw,
                                                    int* __restrict__ flag) {
    int any = 0;
#pragma unroll
    for (int k = 0; k < 64; ++k) {
        int i = threadIdx.x + k * 256;          // first 16384 qwords
        any |= raw[2 * i + 1];
    }
    unsigned long long b = __ballot(any != 0);
    __shared__ int acc[4];
    int w = threadIdx.x >> 6;
    if ((threadIdx.x & 63) == 0) acc[w] = (b != 0ULL) ? 1 : 0;
    __syncthreads();
    if (threadIdx.x == 0) *flag = acc[0] | acc[1] | acc[2] | acc[3];
}

__global__ void zero_counts(int* __restrict__ counts) {
    int i = blockIdx.x * blockDim.x + threadIdx.x;
    if (i < N) counts[i] = 0;
}

__global__ void count_deg(const int* __restrict__ raw, const int* __restrict__ flag,
                          int* __restrict__ counts) {
    int e = blockIdx.x * blockDim.x + threadIdx.x;
    if (e >= E) return;
    int is32 = *flag;
    int d = is32 ? raw[E + e] : raw[2 * ((long long)E + e)];
    atomicAdd(&counts[d], 1);
}

// Block-local inclusive scan (Hillis-Steele over 256 entries in LDS).
__global__ __launch_bounds__(256) void scan1(const int* __restrict__ counts,
                                             int* __restrict__ rowstart,
                                             int* __restrict__ bsum) {
    __shared__ int tmp[256];
    int t = threadIdx.x;
    int i = blockIdx.x * 256 + t;
    int v = (i < N) ? counts[i] : 0;
    tmp[t] = v;
    __syncthreads();
#pragma unroll
    for (int off = 1; off < 256; off <<= 1) {
        int a = (t >= off) ? tmp[t - off] : 0;
        __syncthreads();
        tmp[t] += a;
        __syncthreads();
    }
    if (i < N) rowstart[i] = tmp[t] - v;          // exclusive within block
    if (t == 255) bsum[blockIdx.x] = tmp[255];    // block total
}

__global__ __launch_bounds__(512) void scan2(int* __restrict__ bsum) {
    __shared__ int tmp[512];
    int t = threadIdx.x;
    int v = (t < NBLK) ? bsum[t] : 0;
    tmp[t] = v;
    __syncthreads();
#pragma unroll
    for (int off = 1; off < 512; off <<= 1) {
        int a = (t >= off) ? tmp[t - off] : 0;
        __syncthreads();
        tmp[t] += a;
        __syncthreads();
    }
    if (t < NBLK) bsum[t] = tmp[t] - v;           // exclusive block offsets
}

__global__ void scan3(int* __restrict__ rowstart, const int* __restrict__ bsum,
                      int* __restrict__ cursor) {
    int i = blockIdx.x * blockDim.x + threadIdx.x;
    if (i < N) {
        rowstart[i] += bsum[i >> 8];
        cursor[i] = 0;                            // counts recycled as cursor
    }
    if (i == 0) rowstart[N] = E;
}

__global__ void fill_csr(const int* __restrict__ raw, const int* __restrict__ flag,
                         const int* __restrict__ rowstart, int* __restrict__ cursor,
                         int* __restrict__ csr) {
    int e = blockIdx.x * blockDim.x + threadIdx.x;
    if (e >= E) return;
    int is32 = *flag;
    int s, d;
    if (is32) {
        s = raw[e];
        d = raw[E + e];
    } else {
        s = raw[2 * (long long)e];
        d = raw[2 * ((long long)E + e)];
    }
    int pos = rowstart[d] + atomicAdd(&cursor[d], 1);
    csr[pos] = s;
}

// ---------------- layer 1 transform: z1 = x@W1l^T, r1 = x@W1r^T ----------------
// Tile of 32 nodes staged in LDS; wave computes col `lane` for 8 nodes
// (2 passes x 4-node batch). W fragments amortized over the 4-node batch.
__global__ __launch_bounds__(256, 4) void transform1(
        const float* __restrict__ x, const float* __restrict__ W1l,
        const float* __restrict__ W1r, float* __restrict__ z1,
        float* __restrict__ r1) {
    __shared__ float4 wl4[32 * 64];   // wl4[k4*64 + j] = W1l[j][4k4..4k4+3]
    __shared__ float4 wr4[32 * 64];
    __shared__ float4 xs[32][32];     // 32 nodes x 128 feats
    const float4* Wl = (const float4*)W1l;   // [64][32] float4
    const float4* Wr = (const float4*)W1r;
    for (int idx = threadIdx.x; idx < 2048; idx += 256) {
        int j = idx & 63, k4 = idx >> 6;
        wl4[k4 * 64 + j] = Wl[j * 32 + k4];
        wr4[k4 * 64 + j] = Wr[j * 32 + k4];
    }
    const int lane = threadIdx.x & 63;
    const int wave = threadIdx.x >> 6;
    const float4* x4 = (const float4*)x;     // [N][32]

    for (int tile = blockIdx.x; tile < T1_TILES; tile += gridDim.x) {
        __syncthreads();   // xs reuse from previous tile (and W stage, first iter)
#pragma unroll
        for (int r = 0; r < 4; ++r) {
            int idx = threadIdx.x + r * 256;
            int nn = idx >> 5, k4 = idx & 31;
            xs[nn][k4] = x4[((size_t)tile * 32 + nn) * 32 + k4];
        }
        __syncthreads();
#pragma unroll
        for (int pass = 0; pass < 2; ++pass) {
            const int nb = wave * 8 + pass * 4;
            float a0 = 0.f, a1 = 0.f, a2 = 0.f, a3 = 0.f;
            float b0 = 0.f, b1 = 0.f, b2 = 0.f, b3 = 0.f;
            for (int k4 = 0; k4 < 32; ++k4) {
                float4 wlv = wl4[k4 * 64 + lane];
                float4 wrv = wr4[k4 * 64 + lane];
                float4 x0 = xs[nb + 0][k4];
                float4 x1 = xs[nb + 1][k4];
                float4 x2 = xs[nb + 2][k4];
                float4 x3 = xs[nb + 3][k4];
                a0 += wlv.x * x0.x + wlv.y * x0.y + wlv.z * x0.z + wlv.w * x0.w;
                a1 += wlv.x * x1.x + wlv.y * x1.y + wlv.z * x1.z + wlv.w * x1.w;
                a2 += wlv.x * x2.x + wlv.y * x2.y + wlv.z * x2.z + wlv.w * x2.w;
                a3 += wlv.x * x3.x + wlv.y * x3.y + wlv.z * x3.z + wlv.w * x3.w;
                b0 += wrv.x * x0.x + wrv.y * x0.y + wrv.z * x0.z + wrv.w * x0.w;
                b1 += wrv.x * x1.x + wrv.y * x1.y + wrv.z * x1.z + wrv.w * x1.w;
                b2 += wrv.x * x2.x + wrv.y * x2.y + wrv.z * x2.z + wrv.w * x2.w;
                b3 += wrv.x * x3.x + wrv.y * x3.y + wrv.z * x3.z + wrv.w * x3.w;
            }
            size_t base = ((size_t)tile * 32 + nb) * 64 + lane;
            z1[base] = a0; z1[base + 64] = a1; z1[base + 128] = a2; z1[base + 192] = a3;
            r1[base] = b0; r1[base + 64] = b1; r1[base + 128] = b2; r1[base + 192] = b3;
        }
    }
}

// ---------------- layer 2 transform: z2 = h@W2l^T, r2 = h@W2r^T ----------------
// 64-node LDS tile; lanes 0..31 -> z2 cols, 32..63 -> r2 cols; wave computes
// 16 nodes (2 passes x 8-node batch), one W fragment per k4 per batch.
__global__ __launch_bounds__(256, 4) void transform2(
        const float* __restrict__ h, const float* __restrict__ W2l,
        const float* __restrict__ W2r, float* __restrict__ z2,
        float* __restrict__ r2) {
    __shared__ float4 wc4[16 * 64];
    __shared__ float4 xs[64][16];     // 64 nodes x 64 feats
    const float4* Wl = (const float4*)W2l;   // [32][16] float4
    const float4* Wr = (const float4*)W2r;
    for (int idx = threadIdx.x; idx < 1024; idx += 256) {
        int j = idx & 63, k4 = idx >> 6;
        wc4[k4 * 64 + j] = (j < 32) ? Wl[j * 16 + k4] : Wr[(j - 32) * 16 + k4];
    }
    const int lane = threadIdx.x & 63;
    const int wave = threadIdx.x >> 6;
    const float4* h4 = (const float4*)h;     // [N][16]

    for (int tile = blockIdx.x; tile < T2_TILES; tile += gridDim.x) {
        __syncthreads();
#pragma unroll
        for (int r = 0; r < 4; ++r) {
            int idx = threadIdx.x + r * 256;
            int nn = idx >> 4, k4 = idx & 15;
            int n = tile * 64 + nn;
            xs[nn][k4] = (n < N) ? h4[(size_t)n * 16 + k4]
                                 : make_float4(0.f, 0.f, 0.f, 0.f);
        }
        __syncthreads();
#pragma unroll
        for (int pass = 0; pass < 2; ++pass) {
            const int nb = wave * 16 + pass * 8;
            float acc[8];
#pragma unroll
            for (int u = 0; u < 8; ++u) acc[u] = 0.f;
            for (int k4 = 0; k4 < 16; ++k4) {
                float4 wv = wc4[k4 * 64 + lane];
#pragma unroll
                for (int u = 0; u < 8; ++u) {
                    float4 hq = xs[nb + u][k4];
                    acc[u] += wv.x * hq.x + wv.y * hq.y + wv.z * hq.z + wv.w * hq.w;
                }
            }
#pragma unroll
            for (int u = 0; u < 8; ++u) {
                int n = tile * 64 + nb + u;
                if (n < N) {
                    if (lane < 32) z2[(size_t)n * 32 + lane] = acc[u];
                    else           r2[(size_t)n * 32 + (lane - 32)] = acc[u];
                }
            }
        }
    }
}

// ---------------- fused CSR-gather aggregation ----------------

// Layer 1: wave per node, lane = feature j (64 feats).
__global__ __launch_bounds__(256) void agg1_fused(
        const int* __restrict__ rowstart, const int* __restrict__ csr,
        const float* __restrict__ z1, const float* __restrict__ r1,
        const float* __restrict__ b1, float* __restrict__ h) {
    const int n = blockIdx.x * 4 + (threadIdx.x >> 6);
    if (n >= N) return;
    const int j = threadIdx.x & 63;
    const int beg = rowstart[n], end = rowstart[n + 1];
    float s = 0.f;
    int p = beg;
    for (; p + 4 <= end; p += 4) {
        int c0 = csr[p], c1 = csr[p + 1], c2 = csr[p + 2], c3 = csr[p + 3];
        s += z1[(size_t)c0 * 64 + j] + z1[(size_t)c1 * 64 + j]
           + z1[(size_t)c2 * 64 + j] + z1[(size_t)c3 * 64 + j];
    }
    for (; p < end; ++p) s += z1[(size_t)csr[p] * 64 + j];
    float m = (end > beg) ? s / (float)(end - beg) : 0.f;
    size_t o = (size_t)n * 64 + j;
    h[o] = fmaxf(m + b1[j] + r1[o], 0.f);
}

// Layer 2: half-wave per node (32 feats), wave handles 2 nodes.
__global__ __launch_bounds__(256) void agg2_fused(
        const int* __restrict__ rowstart, const int* __restrict__ csr,
        const float* __restrict__ z2, const float* __restrict__ r2,
        const float* __restrict__ b2, float* __restrict__ out) {
    const int wid = blockIdx.x * 4 + (threadIdx.x >> 6);
    const int n = wid * 2 + ((threadIdx.x >> 5) & 1);
    if (n >= N) return;
    const int j = threadIdx.x & 31;
    const int beg = rowstart[n], end = rowstart[n + 1];
    float s = 0.f;
    int p = beg;
    for (; p + 4 <= end; p += 4) {
        int c0 = csr[p], c1 = csr[p + 1], c2 = csr[p + 2], c3 = csr[p + 3];
        s += z2[(size_t)c0 * 32 + j] + z2[(size_t)c1 * 32 + j]
           + z2[(size_t)c2 * 32 + j] + z2[(size_t)c3 * 32 + j];
    }
    for (; p < end; ++p) s += z2[(size_t)csr[p] * 32 + j];
    float m = (end > beg) ? s / (float)(end - beg) : 0.f;
    size_t o = (size_t)n * 32 + j;
    out[o] = m + b2[j] + r2[o];
}

// ---------------- launch ----------------

extern "C" void kernel_launch(void* const* d_in, const int* in_sizes, int n_in,
                              void* d_out, int out_size, void* d_ws, size_t ws_size,
                              hipStream_t stream) {
    const float* x    = (const float*)d_in[0];
    const int*   raw  = (const int*)d_in[1];
    const float* W1l  = (const float*)d_in[2];
    const float* b1   = (const float*)d_in[3];
    const float* W1r  = (const float*)d_in[4];
    const float* W2l  = (const float*)d_in[5];
    const float* b2   = (const float*)d_in[6];
    const float* W2r  = (const float*)d_in[7];
    float* out = (float*)d_out;

    float* ws = (float*)d_ws;
    float* z1 = ws;                    // [N*64]
    float* r1 = ws + NF64;             // [N*64]
    float* h  = ws + 2 * NF64;         // [N*64]
    float* z2 = ws;                    // reuse z1 space [N*32]
    float* r2 = ws + NF32;             // reuse z1 space [N*32]

    int* ibase    = (int*)(ws + 3 * NF64);
    int* counts   = ibase;                   // [N], recycled as cursor
    int* rowstart = ibase + N;               // [N+1]
    int* bsum     = ibase + 2 * N + 1;       // [512]
    int* csr      = ibase + 2 * N + 1 + 512; // [E]
    int* flag     = csr + E;                 // [1]

    const int eb = (E + 255) / 256;

    detect_dtype<<<1, 256, 0, stream>>>(raw, flag);
    zero_counts<<<NBLK, 256, 0, stream>>>(counts);
    count_deg<<<eb, 256, 0, stream>>>(raw, flag, counts);
    scan1<<<NBLK, 256, 0, stream>>>(counts, rowstart, bsum);
    scan2<<<1, 512, 0, stream>>>(bsum);
    scan3<<<NBLK, 256, 0, stream>>>(rowstart, bsum, counts);
    fill_csr<<<eb, 256, 0, stream>>>(raw, flag, rowstart, counts, csr);

    transform1<<<512, 256, 0, stream>>>(x, W1l, W1r, z1, r1);
    agg1_fused<<<(N + 3) / 4, 256, 0, stream>>>(rowstart, csr, z1, r1, b1, h);

    transform2<<<1024, 256, 0, stream>>>(h, W2l, W2r, z2, r2);
    agg2_fused<<<(N + 7) / 8, 256, 0, stream>>>(rowstart, csr, z2, r2, b2, out);
}

// Round 6
// 473.713 us; speedup vs baseline: 2.0600x; 2.0600x over previous
//
#include <hip/hip_runtime.h>

// GraphSAGE 2-layer, N=100000, E=1600000, 128 -> 64 -> 32.
// Round 6: round-5's LDS-x-tile transforms diverged under graph replay
// (post-timing absmax 0.977) — suspected race in the new tile/store code.
// Revert to round-3's race-surface-free transform structure (W staged in LDS
// once + single barrier, no barriers in the loop, wave-uniform broadcast
// x-loads) and fix its occupancy problem with u=4 unroll (VGPR<=64 instead
// of 256) + 1024-thread blocks for transform1 (64KB LDS -> 2 blk/CU -> 32
// waves/CU). CSR build + agg kernels verbatim from rounds 2-4 (passed
// post-timing three times).

namespace {
constexpr int N = 100000;
constexpr int E = 1600000;
constexpr long long NF64 = (long long)N * 64;   // 6,400,000
constexpr long long NF32 = (long long)N * 32;
constexpr int NBLK = (N + 255) / 256;           // 391 scan blocks
}

// ---------------- CSR build ----------------

// int64 vs int32 edge dtype: high 32-bit words of int64 entries are all zero
// (node ids < 2^31); for int32 data they are random ids. Sample 16384 words,
// single block, one plain store (no atomic storm).
__global__ __launch_bounds__(256) void detect_dtype(const int* __restrict__ raw,
                                                    int* __restrict__ flag) {
    int any = 0;
#pragma unroll
    for (int k = 0; k < 64; ++k) {
        int i = threadIdx.x + k * 256;          // first 16384 qwords
        any |= raw[2 * i + 1];
    }
    unsigned long long b = __ballot(any != 0);
    __shared__ int acc[4];
    int w = threadIdx.x >> 6;
    if ((threadIdx.x & 63) == 0) acc[w] = (b != 0ULL) ? 1 : 0;
    __syncthreads();
    if (threadIdx.x == 0) *flag = acc[0] | acc[1] | acc[2] | acc[3];
}

__global__ void zero_counts(int* __restrict__ counts) {
    int i = blockIdx.x * blockDim.x + threadIdx.x;
    if (i < N) counts[i] = 0;
}

__global__ void count_deg(const int* __restrict__ raw, const int* __restrict__ flag,
                          int* __restrict__ counts) {
    int e = blockIdx.x * blockDim.x + threadIdx.x;
    if (e >= E) return;
    int is32 = *flag;
    int d = is32 ? raw[E + e] : raw[2 * ((long long)E + e)];
    atomicAdd(&counts[d], 1);
}

// Block-local inclusive scan (Hillis-Steele over 256 entries in LDS).
__global__ __launch_bounds__(256) void scan1(const int* __restrict__ counts,
                                             int* __restrict__ rowstart,
                                             int* __restrict__ bsum) {
    __shared__ int tmp[256];
    int t = threadIdx.x;
    int i = blockIdx.x * 256 + t;
    int v = (i < N) ? counts[i] : 0;
    tmp[t] = v;
    __syncthreads();
#pragma unroll
    for (int off = 1; off < 256; off <<= 1) {
        int a = (t >= off) ? tmp[t - off] : 0;
        __syncthreads();
        tmp[t] += a;
        __syncthreads();
    }
    if (i < N) rowstart[i] = tmp[t] - v;          // exclusive within block
    if (t == 255) bsum[blockIdx.x] = tmp[255];    // block total
}

__global__ __launch_bounds__(512) void scan2(int* __restrict__ bsum) {
    __shared__ int tmp[512];
    int t = threadIdx.x;
    int v = (t < NBLK) ? bsum[t] : 0;
    tmp[t] = v;
    __syncthreads();
#pragma unroll
    for (int off = 1; off < 512; off <<= 1) {
        int a = (t >= off) ? tmp[t - off] : 0;
        __syncthreads();
        tmp[t] += a;
        __syncthreads();
    }
    if (t < NBLK) bsum[t] = tmp[t] - v;           // exclusive block offsets
}

__global__ void scan3(int* __restrict__ rowstart, const int* __restrict__ bsum,
                      int* __restrict__ cursor) {
    int i = blockIdx.x * blockDim.x + threadIdx.x;
    if (i < N) {
        rowstart[i] += bsum[i >> 8];
        cursor[i] = 0;                            // counts recycled as cursor
    }
    if (i == 0) rowstart[N] = E;
}

__global__ void fill_csr(const int* __restrict__ raw, const int* __restrict__ flag,
                         const int* __restrict__ rowstart, int* __restrict__ cursor,
                         int* __restrict__ csr) {
    int e = blockIdx.x * blockDim.x + threadIdx.x;
    if (e >= E) return;
    int is32 = *flag;
    int s, d;
    if (is32) {
        s = raw[e];
        d = raw[E + e];
    } else {
        s = raw[2 * (long long)e];
        d = raw[2 * ((long long)E + e)];
    }
    int pos = rowstart[d] + atomicAdd(&cursor[d], 1);
    csr[pos] = s;
}

// ---------------- layer 1 transform: z1 = x@W1l^T, r1 = x@W1r^T ----------------
// Round-3 structure (W in LDS, broadcast x loads, no loop barriers), u=4.
// 1024-thread block: 64KB LDS -> 2 blocks/CU -> 32 waves/CU if VGPR<=64.
__global__ __launch_bounds__(1024) void transform1(
        const float* __restrict__ x, const float* __restrict__ W1l,
        const float* __restrict__ W1r, float* __restrict__ z1,
        float* __restrict__ r1) {
    __shared__ float4 wl4[32 * 64];   // wl4[k4*64 + j] = W1l[j][4k4..4k4+3]
    __shared__ float4 wr4[32 * 64];
    const float4* Wl = (const float4*)W1l;   // [64][32] float4
    const float4* Wr = (const float4*)W1r;
    for (int idx = threadIdx.x; idx < 2048; idx += 1024) {
        int j = idx & 63, k4 = idx >> 6;
        wl4[k4 * 64 + j] = Wl[j * 32 + k4];
        wr4[k4 * 64 + j] = Wr[j * 32 + k4];
    }
    __syncthreads();

    const int lane = threadIdx.x & 63;
    const int wid = blockIdx.x * (blockDim.x >> 6) + (threadIdx.x >> 6);
    const int nWaves = gridDim.x * (blockDim.x >> 6);
    const float4* x4 = (const float4*)x;     // [N][32]

    for (int base = wid * 4; base < N; base += nWaves * 4) {   // N % 4 == 0
        float a0 = 0.f, a1 = 0.f, a2 = 0.f, a3 = 0.f;
        float b0 = 0.f, b1 = 0.f, b2 = 0.f, b3 = 0.f;
        for (int k4 = 0; k4 < 32; ++k4) {
            float4 wlv = wl4[k4 * 64 + lane];
            float4 wrv = wr4[k4 * 64 + lane];
            float4 x0 = x4[(size_t)(base + 0) * 32 + k4];
            float4 x1 = x4[(size_t)(base + 1) * 32 + k4];
            float4 x2 = x4[(size_t)(base + 2) * 32 + k4];
            float4 x3 = x4[(size_t)(base + 3) * 32 + k4];
            a0 += wlv.x * x0.x + wlv.y * x0.y + wlv.z * x0.z + wlv.w * x0.w;
            a1 += wlv.x * x1.x + wlv.y * x1.y + wlv.z * x1.z + wlv.w * x1.w;
            a2 += wlv.x * x2.x + wlv.y * x2.y + wlv.z * x2.z + wlv.w * x2.w;
            a3 += wlv.x * x3.x + wlv.y * x3.y + wlv.z * x3.z + wlv.w * x3.w;
            b0 += wrv.x * x0.x + wrv.y * x0.y + wrv.z * x0.z + wrv.w * x0.w;
            b1 += wrv.x * x1.x + wrv.y * x1.y + wrv.z * x1.z + wrv.w * x1.w;
            b2 += wrv.x * x2.x + wrv.y * x2.y + wrv.z * x2.z + wrv.w * x2.w;
            b3 += wrv.x * x3.x + wrv.y * x3.y + wrv.z * x3.z + wrv.w * x3.w;
        }
        size_t o = (size_t)base * 64 + lane;
        z1[o] = a0; z1[o + 64] = a1; z1[o + 128] = a2; z1[o + 192] = a3;
        r1[o] = b0; r1[o + 64] = b1; r1[o + 128] = b2; r1[o + 192] = b3;
    }
}

// ---------------- layer 2 transform: z2 = h@W2l^T, r2 = h@W2r^T ----------------
// Round-3 structure, u=4. 16KB LDS, small VGPR -> high occupancy.
__global__ __launch_bounds__(256) void transform2(
        const float* __restrict__ h, const float* __restrict__ W2l,
        const float* __restrict__ W2r, float* __restrict__ z2,
        float* __restrict__ r2) {
    __shared__ float4 wc4[16 * 64];
    const float4* Wl = (const float4*)W2l;   // [32][16] float4
    const float4* Wr = (const float4*)W2r;
    for (int idx = threadIdx.x; idx < 1024; idx += 256) {
        int j = idx & 63, k4 = idx >> 6;
        wc4[k4 * 64 + j] = (j < 32) ? Wl[j * 16 + k4] : Wr[(j - 32) * 16 + k4];
    }
    __syncthreads();

    const int lane = threadIdx.x & 63;
    const int wid = blockIdx.x * (blockDim.x >> 6) + (threadIdx.x >> 6);
    const int nWaves = gridDim.x * (blockDim.x >> 6);
    const float4* h4 = (const float4*)h;     // [N][16]

    for (int base = wid * 4; base < N; base += nWaves * 4) {
        float a0 = 0.f, a1 = 0.f, a2 = 0.f, a3 = 0.f;
        for (int k4 = 0; k4 < 16; ++k4) {
            float4 wv = wc4[k4 * 64 + lane];
            float4 h0 = h4[(size_t)(base + 0) * 16 + k4];
            float4 h1 = h4[(size_t)(base + 1) * 16 + k4];
            float4 h2 = h4[(size_t)(base + 2) * 16 + k4];
            float4 h3 = h4[(size_t)(base + 3) * 16 + k4];
            a0 += wv.x * h0.x + wv.y * h0.y + wv.z * h0.z + wv.w * h0.w;
            a1 += wv.x * h1.x + wv.y * h1.y + wv.z * h1.z + wv.w * h1.w;
            a2 += wv.x * h2.x + wv.y * h2.y + wv.z * h2.z + wv.w * h2.w;
            a3 += wv.x * h3.x + wv.y * h3.y + wv.z * h3.z + wv.w * h3.w;
        }
        if (lane < 32) {
            z2[(size_t)(base + 0) * 32 + lane] = a0;
            z2[(size_t)(base + 1) * 32 + lane] = a1;
            z2[(size_t)(base + 2) * 32 + lane] = a2;
            z2[(size_t)(base + 3) * 32 + lane] = a3;
        } else {
            int jj = lane - 32;
            r2[(size_t)(base + 0) * 32 + jj] = a0;
            r2[(size_t)(base + 1) * 32 + jj] = a1;
            r2[(size_t)(base + 2) * 32 + jj] = a2;
            r2[(size_t)(base + 3) * 32 + jj] = a3;
        }
    }
}

// ---------------- fused CSR-gather aggregation ----------------

// Layer 1: wave per node, lane = feature j (64 feats).
__global__ __launch_bounds__(256) void agg1_fused(
        const int* __restrict__ rowstart, const int* __restrict__ csr,
        const float* __restrict__ z1, const float* __restrict__ r1,
        const float* __restrict__ b1, float* __restrict__ h) {
    const int n = blockIdx.x * 4 + (threadIdx.x >> 6);
    if (n >= N) return;
    const int j = threadIdx.x & 63;
    const int beg = rowstart[n], end = rowstart[n + 1];
    float s = 0.f;
    int p = beg;
    for (; p + 4 <= end; p += 4) {
        int c0 = csr[p], c1 = csr[p + 1], c2 = csr[p + 2], c3 = csr[p + 3];
        s += z1[(size_t)c0 * 64 + j] + z1[(size_t)c1 * 64 + j]
           + z1[(size_t)c2 * 64 + j] + z1[(size_t)c3 * 64 + j];
    }
    for (; p < end; ++p) s += z1[(size_t)csr[p] * 64 + j];
    float m = (end > beg) ? s / (float)(end - beg) : 0.f;
    size_t o = (size_t)n * 64 + j;
    h[o] = fmaxf(m + b1[j] + r1[o], 0.f);
}

// Layer 2: half-wave per node (32 feats), wave handles 2 nodes.
__global__ __launch_bounds__(256) void agg2_fused(
        const int* __restrict__ rowstart, const int* __restrict__ csr,
        const float* __restrict__ z2, const float* __restrict__ r2,
        const float* __restrict__ b2, float* __restrict__ out) {
    const int wid = blockIdx.x * 4 + (threadIdx.x >> 6);
    const int n = wid * 2 + ((threadIdx.x >> 5) & 1);
    if (n >= N) return;
    const int j = threadIdx.x & 31;
    const int beg = rowstart[n], end = rowstart[n + 1];
    float s = 0.f;
    int p = beg;
    for (; p + 4 <= end; p += 4) {
        int c0 = csr[p], c1 = csr[p + 1], c2 = csr[p + 2], c3 = csr[p + 3];
        s += z2[(size_t)c0 * 32 + j] + z2[(size_t)c1 * 32 + j]
           + z2[(size_t)c2 * 32 + j] + z2[(size_t)c3 * 32 + j];
    }
    for (; p < end; ++p) s += z2[(size_t)csr[p] * 32 + j];
    float m = (end > beg) ? s / (float)(end - beg) : 0.f;
    size_t o = (size_t)n * 32 + j;
    out[o] = m + b2[j] + r2[o];
}

// ---------------- launch ----------------

extern "C" void kernel_launch(void* const* d_in, const int* in_sizes, int n_in,
                              void* d_out, int out_size, void* d_ws, size_t ws_size,
                              hipStream_t stream) {
    const float* x    = (const float*)d_in[0];
    const int*   raw  = (const int*)d_in[1];
    const float* W1l  = (const float*)d_in[2];
    const float* b1   = (const float*)d_in[3];
    const float* W1r  = (const float*)d_in[4];
    const float* W2l  = (const float*)d_in[5];
    const float* b2   = (const float*)d_in[6];
    const float* W2r  = (const float*)d_in[7];
    float* out = (float*)d_out;

    float* ws = (float*)d_ws;
    float* z1 = ws;                    // [N*64]
    float* r1 = ws + NF64;             // [N*64]
    float* h  = ws + 2 * NF64;         // [N*64]
    float* z2 = ws;                    // reuse z1 space [N*32]
    float* r2 = ws + NF32;             // reuse z1 space [N*32]

    int* ibase    = (int*)(ws + 3 * NF64);
    int* counts   = ibase;                   // [N], recycled as cursor
    int* rowstart = ibase + N;               // [N+1]
    int* bsum     = ibase + 2 * N + 1;       // [512]
    int* csr      = ibase + 2 * N + 1 + 512; // [E]
    int* flag     = csr + E;                 // [1]

    const int eb = (E + 255) / 256;

    detect_dtype<<<1, 256, 0, stream>>>(raw, flag);
    zero_counts<<<NBLK, 256, 0, stream>>>(counts);
    count_deg<<<eb, 256, 0, stream>>>(raw, flag, counts);
    scan1<<<NBLK, 256, 0, stream>>>(counts, rowstart, bsum);
    scan2<<<1, 512, 0, stream>>>(bsum);
    scan3<<<NBLK, 256, 0, stream>>>(rowstart, bsum, counts);
    fill_csr<<<eb, 256, 0, stream>>>(raw, flag, rowstart, counts, csr);

    transform1<<<512, 1024, 0, stream>>>(x, W1l, W1r, z1, r1);
    agg1_fused<<<(N + 3) / 4, 256, 0, stream>>>(rowstart, csr, z1, r1, b1, h);

    transform2<<<2048, 256, 0, stream>>>(h, W2l, W2r, z2, r2);
    agg2_fused<<<(N + 7) / 8, 256, 0, stream>>>(rowstart, csr, z2, r2, b2, out);
}